// Round 1
// baseline (94.279 us; speedup 1.0000x reference)
//
#include <hip/hip_runtime.h>

// Problem: B=32 rows, N=8192 elems/row, select top-K=256 per row.
// Forward value of the straight-through estimator == hard (one-hot sum) + mem.
// Exact per-row radix select (4 x 8-bit passes) on monotone uint keys.

#define BB 32
#define NN 8192
#define KK 256
#define THREADS 1024
#define EPT 8   // elements per thread, contiguous: thread t owns [8t, 8t+8)

__device__ __forceinline__ unsigned float_to_key(float f) {
    unsigned u = __float_as_uint(f);
    // monotone map: larger float -> larger uint
    return (u & 0x80000000u) ? ~u : (u | 0x80000000u);
}

__global__ __launch_bounds__(THREADS) void topk_hard_kernel(
    const float* __restrict__ logits,
    const float* __restrict__ noise,
    const float* __restrict__ mem,
    float* __restrict__ out)
{
    __shared__ unsigned hist[256];
    __shared__ unsigned scanbuf[THREADS];
    __shared__ unsigned sh_prefix;
    __shared__ unsigned sh_need;

    const int row  = blockIdx.x;
    const int tid  = threadIdx.x;
    const int base = row * NN + tid * EPT;

    // ---- load (2x float4 per input, fully coalesced 16B/lane) ----
    float4 lg0 = ((const float4*)(logits + base))[0];
    float4 lg1 = ((const float4*)(logits + base))[1];
    float4 no0 = ((const float4*)(noise  + base))[0];
    float4 no1 = ((const float4*)(noise  + base))[1];
    float4 mm0 = ((const float4*)(mem    + base))[0];
    float4 mm1 = ((const float4*)(mem    + base))[1];

    float p[EPT];
    p[0] = lg0.x + no0.x + mm0.x * -1000.0f;
    p[1] = lg0.y + no0.y + mm0.y * -1000.0f;
    p[2] = lg0.z + no0.z + mm0.z * -1000.0f;
    p[3] = lg0.w + no0.w + mm0.w * -1000.0f;
    p[4] = lg1.x + no1.x + mm1.x * -1000.0f;
    p[5] = lg1.y + no1.y + mm1.y * -1000.0f;
    p[6] = lg1.z + no1.z + mm1.z * -1000.0f;
    p[7] = lg1.w + no1.w + mm1.w * -1000.0f;

    unsigned key[EPT];
#pragma unroll
    for (int i = 0; i < EPT; ++i) key[i] = float_to_key(p[i]);

    // ---- 4-pass radix select: find threshold key T (K-th largest) ----
    unsigned need   = KK;  // how many of the current candidate set still needed
    unsigned prefix = 0;   // chosen high bits of T so far

    for (int level = 0; level < 4; ++level) {
        const int shift = 24 - 8 * level;

        if (tid < 256) hist[tid] = 0;
        __syncthreads();

#pragma unroll
        for (int i = 0; i < EPT; ++i) {
            bool part = (level == 0) ||
                        ((key[i] >> (shift + 8)) == (prefix >> (shift + 8)));
            if (part) atomicAdd(&hist[(key[i] >> shift) & 0xFFu], 1u);
        }
        __syncthreads();

        if (tid == 0) {
            unsigned acc = 0;
            int d = 255;
            for (; d > 0; --d) {
                unsigned c = hist[d];
                if (acc + c >= need) break;
                acc += c;
            }
            sh_prefix = prefix | ((unsigned)d << shift);
            sh_need   = need - acc;
        }
        __syncthreads();
        prefix = sh_prefix;
        need   = sh_need;
        // hist re-zero at top of next level has its own barrier protecting sh_*
    }

    const unsigned T = prefix;          // exact K-th largest key
    // need = number of keys == T that belong to top-K (take lowest indices)

    // ---- exclusive scan of per-thread equal counts (index-order tiebreak) ----
    unsigned local_eq = 0;
#pragma unroll
    for (int i = 0; i < EPT; ++i) local_eq += (key[i] == T) ? 1u : 0u;

    scanbuf[tid] = local_eq;
    __syncthreads();
    for (int off = 1; off < THREADS; off <<= 1) {
        unsigned v = (tid >= off) ? scanbuf[tid - off] : 0u;
        __syncthreads();
        scanbuf[tid] += v;
        __syncthreads();
    }
    unsigned rank = scanbuf[tid] - local_eq;  // exclusive prefix of equals

    // ---- emit: out = indicator(top-K) + sample_memory ----
    float o[EPT];
#pragma unroll
    for (int i = 0; i < EPT; ++i) {
        float sel;
        if (key[i] > T) {
            sel = 1.0f;
        } else if (key[i] == T) {
            sel = (rank < need) ? 1.0f : 0.0f;
            ++rank;
        } else {
            sel = 0.0f;
        }
        o[i] = sel;
    }
    o[0] += mm0.x; o[1] += mm0.y; o[2] += mm0.z; o[3] += mm0.w;
    o[4] += mm1.x; o[5] += mm1.y; o[6] += mm1.z; o[7] += mm1.w;

    float4 o0 = make_float4(o[0], o[1], o[2], o[3]);
    float4 o1 = make_float4(o[4], o[5], o[6], o[7]);
    ((float4*)(out + base))[0] = o0;
    ((float4*)(out + base))[1] = o1;
}

extern "C" void kernel_launch(void* const* d_in, const int* in_sizes, int n_in,
                              void* d_out, int out_size, void* d_ws, size_t ws_size,
                              hipStream_t stream) {
    const float* logits = (const float*)d_in[0];
    const float* noise  = (const float*)d_in[1];
    const float* mem    = (const float*)d_in[2];
    float* out = (float*)d_out;

    topk_hard_kernel<<<BB, THREADS, 0, stream>>>(logits, noise, mem, out);
}

// Round 2
// 65.321 us; speedup vs baseline: 1.4433x; 1.4433x over previous
//
#include <hip/hip_runtime.h>

// B=32 rows, N=8192, K=256. Output of the straight-through estimator
// numerically == hard one-hot-sum + sample_memory (soft terms cancel).
// Exact per-row radix select (4 x 8-bit) on monotone uint keys.
//
// R2: fully parallel select.
//  - level 0 histogram privatized per wave (16x256) -> intra-wave contention only
//  - suffix scan over 256 bins: 256 threads, register combine + __shfl_up
//  - tie-break rank: wave shfl scans + 16 partials (no 1024-wide LDS ladder)

#define BB 32
#define NN 8192
#define KK 256
#define THREADS 1024
#define EPT 8      // thread t owns contiguous indices [8t, 8t+8) -> index-order ties
#define NWAVE 16

__device__ __forceinline__ unsigned float_to_key(float f) {
    unsigned u = __float_as_uint(f);
    return (u & 0x80000000u) ? ~u : (u | 0x80000000u);  // monotone: bigger float -> bigger uint
}

__global__ __launch_bounds__(THREADS) void topk_hard_kernel(
    const float* __restrict__ logits,
    const float* __restrict__ noise,
    const float* __restrict__ mem,
    float* __restrict__ out)
{
    __shared__ unsigned hist[NWAVE][256];   // 16 KB; levels>0 use hist[0] only
    __shared__ unsigned wpart[NWAVE];
    __shared__ unsigned sh_prefix, sh_need;

    const int tid  = threadIdx.x;
    const int wave = tid >> 6;
    const int lane = tid & 63;
    const int base = blockIdx.x * NN + tid * EPT;

    // ---- coalesced float4 loads ----
    float4 lg0 = ((const float4*)(logits + base))[0];
    float4 lg1 = ((const float4*)(logits + base))[1];
    float4 no0 = ((const float4*)(noise  + base))[0];
    float4 no1 = ((const float4*)(noise  + base))[1];
    float4 mm0 = ((const float4*)(mem    + base))[0];
    float4 mm1 = ((const float4*)(mem    + base))[1];

    float p[EPT];
    p[0] = lg0.x + no0.x + mm0.x * -1000.0f;
    p[1] = lg0.y + no0.y + mm0.y * -1000.0f;
    p[2] = lg0.z + no0.z + mm0.z * -1000.0f;
    p[3] = lg0.w + no0.w + mm0.w * -1000.0f;
    p[4] = lg1.x + no1.x + mm1.x * -1000.0f;
    p[5] = lg1.y + no1.y + mm1.y * -1000.0f;
    p[6] = lg1.z + no1.z + mm1.z * -1000.0f;
    p[7] = lg1.w + no1.w + mm1.w * -1000.0f;

    unsigned key[EPT];
#pragma unroll
    for (int i = 0; i < EPT; ++i) key[i] = float_to_key(p[i]);

    // ---- 4-pass radix select for threshold key T ----
    unsigned need   = KK;
    unsigned prefix = 0;

#pragma unroll
    for (int level = 0; level < 4; ++level) {
        const int shift = 24 - 8 * level;

        // zero histograms (16 KB at level 0, 1 KB after)
        if (level == 0) {
            ((uint4*)hist)[tid] = make_uint4(0u, 0u, 0u, 0u);
        } else if (tid < 64) {
            ((uint4*)hist)[tid] = make_uint4(0u, 0u, 0u, 0u);
        }
        __syncthreads();

        if (level == 0) {
            unsigned* h = hist[wave];           // per-wave privatized
#pragma unroll
            for (int i = 0; i < EPT; ++i)
                atomicAdd(&h[key[i] >> 24], 1u);
        } else {
            const unsigned hi = prefix >> (shift + 8);
#pragma unroll
            for (int i = 0; i < EPT; ++i)
                if ((key[i] >> (shift + 8)) == hi)
                    atomicAdd(&hist[0][(key[i] >> shift) & 255u], 1u);
        }
        __syncthreads();

        // parallel suffix scan: thread t (t<256) owns digit d = 255-t.
        unsigned c = 0, s = 0;
        if (tid < 256) {
            const int d = 255 - tid;
            if (level == 0) {
#pragma unroll
                for (int w = 0; w < NWAVE; ++w) c += hist[w][d];
            } else {
                c = hist[0][d];
            }
            s = c;  // inclusive scan over t  ==  suffix sum S[d]
#pragma unroll
            for (int off = 1; off < 64; off <<= 1) {
                unsigned nv = __shfl_up(s, off, 64);
                if (lane >= off) s += nv;
            }
            if (lane == 63) wpart[wave] = s;    // wave in 0..3 here
        }
        __syncthreads();
        if (tid < 256) {
            for (int w = 0; w < wave; ++w) s += wpart[w];
            const unsigned snext = s - c;       // S[d+1]
            if (s >= need && snext < need) {    // unique crossing thread
                sh_prefix = prefix | ((unsigned)(255 - tid) << shift);
                sh_need   = need - snext;
            }
        }
        __syncthreads();
        prefix = sh_prefix;
        need   = sh_need;
    }

    const unsigned T = prefix;   // exact K-th largest key; `need` = #ties to keep

    // ---- tie-break rank: exclusive count of (key==T) at lower index ----
    unsigned local_eq = 0;
#pragma unroll
    for (int i = 0; i < EPT; ++i) local_eq += (key[i] == T) ? 1u : 0u;

    unsigned s2 = local_eq;
#pragma unroll
    for (int off = 1; off < 64; off <<= 1) {
        unsigned nv = __shfl_up(s2, off, 64);
        if (lane >= off) s2 += nv;
    }
    if (lane == 63) wpart[wave] = s2;
    __syncthreads();
    unsigned radd = 0;
    for (int w = 0; w < wave; ++w) radd += wpart[w];
    unsigned rank = s2 - local_eq + radd;   // exclusive prefix over thread order

    // ---- emit: out = indicator(top-K) + sample_memory ----
    float o[EPT];
#pragma unroll
    for (int i = 0; i < EPT; ++i) {
        float sel;
        if (key[i] > T) {
            sel = 1.0f;
        } else if (key[i] == T) {
            sel = (rank < need) ? 1.0f : 0.0f;
            ++rank;
        } else {
            sel = 0.0f;
        }
        o[i] = sel;
    }
    o[0] += mm0.x; o[1] += mm0.y; o[2] += mm0.z; o[3] += mm0.w;
    o[4] += mm1.x; o[5] += mm1.y; o[6] += mm1.z; o[7] += mm1.w;

    ((float4*)(out + base))[0] = make_float4(o[0], o[1], o[2], o[3]);
    ((float4*)(out + base))[1] = make_float4(o[4], o[5], o[6], o[7]);
}

extern "C" void kernel_launch(void* const* d_in, const int* in_sizes, int n_in,
                              void* d_out, int out_size, void* d_ws, size_t ws_size,
                              hipStream_t stream) {
    const float* logits = (const float*)d_in[0];
    const float* noise  = (const float*)d_in[1];
    const float* mem    = (const float*)d_in[2];
    float* out = (float*)d_out;

    topk_hard_kernel<<<BB, THREADS, 0, stream>>>(logits, noise, mem, out);
}

// Round 4
// 64.754 us; speedup vs baseline: 1.4560x; 1.0088x over previous
//
#include <hip/hip_runtime.h>

// B=32 rows, N=8192, K=256. Straight-through estimator forward value
// == hard one-hot-sum + sample_memory (soft terms cancel numerically).
// Exact per-row radix select (8-bit level 0 + 3 refine levels) on
// monotone uint keys.
//
// R4 = R3 (two-stage full-chip) hardened:
//  - all __shared__ arrays __align__(16) (LDS b128 access UB fix)
//  - pick_digit uses scalar LDS reads
//  - host-side ws_size guard -> fallback to the proven single-kernel path

#define NROW 32
#define NCOL 8192
#define KSEL 256

__device__ __forceinline__ unsigned float_to_key(float f) {
    unsigned u = __float_as_uint(f);
    return (u & 0x80000000u) ? ~u : (u | 0x80000000u);  // monotone
}

// ---------------- K1: keys + per-block private hist + out=mem ----------------
__global__ __launch_bounds__(256) void stage1(
    const float* __restrict__ logits, const float* __restrict__ noise,
    const float* __restrict__ mem, float* __restrict__ out,
    unsigned* __restrict__ keys, unsigned* __restrict__ ghist)
{
    __shared__ __align__(16) unsigned h[4][256];
    const int tid  = threadIdx.x;
    const int wave = tid >> 6;
    const int base = blockIdx.x * 1024 + tid * 4;

    float4 lg = *(const float4*)(logits + base);
    float4 no = *(const float4*)(noise  + base);
    float4 mm = *(const float4*)(mem    + base);

    ((uint4*)h)[tid] = make_uint4(0u, 0u, 0u, 0u);

    unsigned k0 = float_to_key(lg.x + no.x + mm.x * -1000.0f);
    unsigned k1 = float_to_key(lg.y + no.y + mm.y * -1000.0f);
    unsigned k2 = float_to_key(lg.z + no.z + mm.z * -1000.0f);
    unsigned k3 = float_to_key(lg.w + no.w + mm.w * -1000.0f);

    *(float4*)(out  + base) = mm;                      // prefill out = mem
    *(uint4*)(keys + base) = make_uint4(k0, k1, k2, k3);

    __syncthreads();
    unsigned* hw = h[wave];
    atomicAdd(&hw[k0 >> 24], 1u);
    atomicAdd(&hw[k1 >> 24], 1u);
    atomicAdd(&hw[k2 >> 24], 1u);
    atomicAdd(&hw[k3 >> 24], 1u);
    __syncthreads();

    ghist[blockIdx.x * 256 + tid] =
        h[0][tid] + h[1][tid] + h[2][tid] + h[3][tid];
}

// Wave 0 only: suffix scan of 256 bins (descending digits), find crossing of
// `need`; publish {prefix|digit<<shift, residual need} to sh_pn[0..1].
__device__ __forceinline__ void pick_digit(const unsigned* h, unsigned prefix,
                                           unsigned need, int shift,
                                           unsigned* sh_pn)
{
    const int lane = threadIdx.x & 63;
    const int d0   = 255 - 4 * lane;           // this lane's highest digit
    unsigned c0 = h[d0];
    unsigned c1 = h[d0 - 1];
    unsigned c2 = h[d0 - 2];
    unsigned c3 = h[d0 - 3];
    unsigned tot = c0 + c1 + c2 + c3;
    unsigned s = tot;                          // inclusive scan over lanes
#pragma unroll
    for (int off = 1; off < 64; off <<= 1) {
        unsigned nv = __shfl_up(s, off, 64);
        if (lane >= off) s += nv;
    }
    unsigned P    = s - tot;                   // suffix sum of higher digits
    unsigned cum0 = P + c0;
    unsigned cum1 = cum0 + c1;
    unsigned cum2 = cum1 + c2;
    unsigned cum3 = cum2 + c3;
    unsigned d = 0, nn = 0;
    bool found = false;
    if (cum0 >= need && P < need)          { d = (unsigned)d0;     nn = need - P;    found = true; }
    else if (cum1 >= need && cum0 < need)  { d = (unsigned)d0 - 1; nn = need - cum0; found = true; }
    else if (cum2 >= need && cum1 < need)  { d = (unsigned)d0 - 2; nn = need - cum1; found = true; }
    else if (cum3 >= need && cum2 < need)  { d = (unsigned)d0 - 3; nn = need - cum2; found = true; }
    if (found) {
        sh_pn[0] = prefix | (d << shift);
        sh_pn[1] = nn;
    }
}

// ---------------- K2: combine hists, 3 refine levels, emit ----------------
__global__ __launch_bounds__(1024) void stage2(
    const unsigned* __restrict__ keys, const unsigned* __restrict__ ghist,
    float* __restrict__ out)
{
    __shared__ __align__(16) unsigned hc[256];
    __shared__ __align__(16) unsigned hA[256];
    __shared__ __align__(16) unsigned hB[256];
    __shared__ __align__(16) unsigned wpart[16];
    __shared__ __align__(16) unsigned sh_pn[2];

    const int tid  = threadIdx.x;
    const int wave = tid >> 6;
    const int lane = tid & 63;
    const int base = blockIdx.x * NCOL + tid * 8;

    uint4 ka = ((const uint4*)(keys + base))[0];
    uint4 kb = ((const uint4*)(keys + base))[1];
    unsigned key[8] = {ka.x, ka.y, ka.z, ka.w, kb.x, kb.y, kb.z, kb.w};

    // P0: combine the row's 8 segment histograms; idle threads zero hA
    if (tid < 256) {
        const unsigned* g = ghist + blockIdx.x * 8 * 256 + tid;
        unsigned c = 0;
#pragma unroll
        for (int s = 0; s < 8; ++s) c += g[s * 256];
        hc[tid] = c;
    } else if (tid < 512) {
        hA[tid - 256] = 0u;
    }
    __syncthreads();                                   // B1
    if (wave == 0) pick_digit(hc, 0u, KSEL, 24, sh_pn);
    __syncthreads();                                   // B2
    unsigned prefix = sh_pn[0], need = sh_pn[1];

    // L1: refine bits [23:16] into hA; zero hB concurrently
    if (tid >= 256 && tid < 512) hB[tid - 256] = 0u;
    {
        const unsigned hi = prefix >> 24;
#pragma unroll
        for (int i = 0; i < 8; ++i)
            if ((key[i] >> 24) == hi)
                atomicAdd(&hA[(key[i] >> 16) & 255u], 1u);
    }
    __syncthreads();                                   // B3
    if (wave == 0) pick_digit(hA, prefix, need, 16, sh_pn);
    __syncthreads();                                   // B4
    prefix = sh_pn[0]; need = sh_pn[1];

    // L2: refine bits [15:8] into hB; re-zero hA concurrently
    if (tid >= 256 && tid < 512) hA[tid - 256] = 0u;
    {
        const unsigned hi = prefix >> 16;
#pragma unroll
        for (int i = 0; i < 8; ++i)
            if ((key[i] >> 16) == hi)
                atomicAdd(&hB[(key[i] >> 8) & 255u], 1u);
    }
    __syncthreads();                                   // B5
    if (wave == 0) pick_digit(hB, prefix, need, 8, sh_pn);
    __syncthreads();                                   // B6
    prefix = sh_pn[0]; need = sh_pn[1];

    // L3: refine bits [7:0] into hA
    {
        const unsigned hi = prefix >> 8;
#pragma unroll
        for (int i = 0; i < 8; ++i)
            if ((key[i] >> 8) == hi)
                atomicAdd(&hA[key[i] & 255u], 1u);
    }
    __syncthreads();                                   // B7
    if (wave == 0) pick_digit(hA, prefix, need, 0, sh_pn);
    __syncthreads();                                   // B8
    const unsigned T     = sh_pn[0];   // exact K-th largest key
    const unsigned needF = sh_pn[1];   // ties kept at lowest indices

    // tie-break: exclusive count of equal keys at lower index
    unsigned local_eq = 0;
#pragma unroll
    for (int i = 0; i < 8; ++i) local_eq += (key[i] == T) ? 1u : 0u;
    unsigned s2 = local_eq;
#pragma unroll
    for (int off = 1; off < 64; off <<= 1) {
        unsigned nv = __shfl_up(s2, off, 64);
        if (lane >= off) s2 += nv;
    }
    if (lane == 63) wpart[wave] = s2;
    __syncthreads();                                   // B9
    unsigned rank = s2 - local_eq;
    for (int w = 0; w < wave; ++w) rank += wpart[w];

    // emit: out already == mem; add 1.0 at selected positions
#pragma unroll
    for (int i = 0; i < 8; ++i) {
        bool sel;
        if (key[i] > T)       sel = true;
        else if (key[i] == T) { sel = (rank < needF); ++rank; }
        else                  sel = false;
        if (sel) atomicAdd(out + base + i, 1.0f);
    }
}

// ---------------- Fallback: proven single-kernel (R2, 65 us) ----------------
__global__ __launch_bounds__(1024) void topk_single(
    const float* __restrict__ logits, const float* __restrict__ noise,
    const float* __restrict__ mem, float* __restrict__ out)
{
    __shared__ __align__(16) unsigned hist[16][256];
    __shared__ __align__(16) unsigned wpart[16];
    __shared__ __align__(16) unsigned sh_pn[2];

    const int tid  = threadIdx.x;
    const int wave = tid >> 6;
    const int lane = tid & 63;
    const int base = blockIdx.x * NCOL + tid * 8;

    float4 lg0 = ((const float4*)(logits + base))[0];
    float4 lg1 = ((const float4*)(logits + base))[1];
    float4 no0 = ((const float4*)(noise  + base))[0];
    float4 no1 = ((const float4*)(noise  + base))[1];
    float4 mm0 = ((const float4*)(mem    + base))[0];
    float4 mm1 = ((const float4*)(mem    + base))[1];

    unsigned key[8];
    key[0] = float_to_key(lg0.x + no0.x + mm0.x * -1000.0f);
    key[1] = float_to_key(lg0.y + no0.y + mm0.y * -1000.0f);
    key[2] = float_to_key(lg0.z + no0.z + mm0.z * -1000.0f);
    key[3] = float_to_key(lg0.w + no0.w + mm0.w * -1000.0f);
    key[4] = float_to_key(lg1.x + no1.x + mm1.x * -1000.0f);
    key[5] = float_to_key(lg1.y + no1.y + mm1.y * -1000.0f);
    key[6] = float_to_key(lg1.z + no1.z + mm1.z * -1000.0f);
    key[7] = float_to_key(lg1.w + no1.w + mm1.w * -1000.0f);

    unsigned need = KSEL, prefix = 0;
#pragma unroll
    for (int level = 0; level < 4; ++level) {
        const int shift = 24 - 8 * level;
        if (level == 0) { hist[tid >> 8][(tid & 255)] = 0u;
                          hist[(tid >> 8) + 4][(tid & 255)] = 0u;
                          hist[(tid >> 8) + 8][(tid & 255)] = 0u;
                          hist[(tid >> 8) + 12][(tid & 255)] = 0u; }
        else if (tid < 256) hist[0][tid] = 0u;
        __syncthreads();
        if (level == 0) {
            unsigned* h = hist[wave];
#pragma unroll
            for (int i = 0; i < 8; ++i) atomicAdd(&h[key[i] >> 24], 1u);
        } else {
            const unsigned hi = prefix >> (shift + 8);
#pragma unroll
            for (int i = 0; i < 8; ++i)
                if ((key[i] >> (shift + 8)) == hi)
                    atomicAdd(&hist[0][(key[i] >> shift) & 255u], 1u);
        }
        __syncthreads();
        if (wave == 0) {
            const int d0 = 255 - 4 * lane;
            unsigned c0, c1, c2, c3;
            if (level == 0) {
                c0 = c1 = c2 = c3 = 0;
#pragma unroll
                for (int w = 0; w < 16; ++w) {
                    c0 += hist[w][d0];     c1 += hist[w][d0 - 1];
                    c2 += hist[w][d0 - 2]; c3 += hist[w][d0 - 3];
                }
            } else {
                c0 = hist[0][d0];     c1 = hist[0][d0 - 1];
                c2 = hist[0][d0 - 2]; c3 = hist[0][d0 - 3];
            }
            unsigned tot = c0 + c1 + c2 + c3, s = tot;
#pragma unroll
            for (int off = 1; off < 64; off <<= 1) {
                unsigned nv = __shfl_up(s, off, 64);
                if (lane >= off) s += nv;
            }
            unsigned P = s - tot;
            unsigned cum0 = P + c0, cum1 = cum0 + c1, cum2 = cum1 + c2, cum3 = cum2 + c3;
            if (cum0 >= need && P < need)         { sh_pn[0] = prefix | ((unsigned)d0 << shift);       sh_pn[1] = need - P; }
            else if (cum1 >= need && cum0 < need) { sh_pn[0] = prefix | ((unsigned)(d0-1) << shift);   sh_pn[1] = need - cum0; }
            else if (cum2 >= need && cum1 < need) { sh_pn[0] = prefix | ((unsigned)(d0-2) << shift);   sh_pn[1] = need - cum1; }
            else if (cum3 >= need && cum2 < need) { sh_pn[0] = prefix | ((unsigned)(d0-3) << shift);   sh_pn[1] = need - cum2; }
        }
        __syncthreads();
        prefix = sh_pn[0]; need = sh_pn[1];
    }
    const unsigned T = prefix, needF = need;

    unsigned local_eq = 0;
#pragma unroll
    for (int i = 0; i < 8; ++i) local_eq += (key[i] == T) ? 1u : 0u;
    unsigned s2 = local_eq;
#pragma unroll
    for (int off = 1; off < 64; off <<= 1) {
        unsigned nv = __shfl_up(s2, off, 64);
        if (lane >= off) s2 += nv;
    }
    if (lane == 63) wpart[wave] = s2;
    __syncthreads();
    unsigned rank = s2 - local_eq;
    for (int w = 0; w < wave; ++w) rank += wpart[w];

    float o[8];
#pragma unroll
    for (int i = 0; i < 8; ++i) {
        float sel;
        if (key[i] > T)       sel = 1.0f;
        else if (key[i] == T) { sel = (rank < needF) ? 1.0f : 0.0f; ++rank; }
        else                  sel = 0.0f;
        o[i] = sel;
    }
    o[0] += mm0.x; o[1] += mm0.y; o[2] += mm0.z; o[3] += mm0.w;
    o[4] += mm1.x; o[5] += mm1.y; o[6] += mm1.z; o[7] += mm1.w;
    ((float4*)(out + base))[0] = make_float4(o[0], o[1], o[2], o[3]);
    ((float4*)(out + base))[1] = make_float4(o[4], o[5], o[6], o[7]);
}

extern "C" void kernel_launch(void* const* d_in, const int* in_sizes, int n_in,
                              void* d_out, int out_size, void* d_ws, size_t ws_size,
                              hipStream_t stream) {
    const float* logits = (const float*)d_in[0];
    const float* noise  = (const float*)d_in[1];
    const float* mem    = (const float*)d_in[2];
    float* out = (float*)d_out;

    const size_t keys_bytes  = (size_t)NROW * NCOL * sizeof(unsigned);   // 1 MB
    const size_t ghist_bytes = (size_t)256 * 256 * sizeof(unsigned);     // 256 KB

    if (ws_size >= keys_bytes + ghist_bytes) {
        unsigned* keys  = (unsigned*)d_ws;
        unsigned* ghist = (unsigned*)((char*)d_ws + keys_bytes);
        stage1<<<256, 256, 0, stream>>>(logits, noise, mem, out, keys, ghist);
        stage2<<<NROW, 1024, 0, stream>>>(keys, ghist, out);
    } else {
        topk_single<<<NROW, 1024, 0, stream>>>(logits, noise, mem, out);
    }
}

// Round 5
// 63.900 us; speedup vs baseline: 1.4754x; 1.0134x over previous
//
#include <hip/hip_runtime.h>

// B=32 rows, N=8192, K=256. Straight-through estimator forward value
// == hard one-hot-sum + sample_memory (soft terms cancel numerically).
//
// R5: single kernel, exact radix select with 12/12/8-bit digits.
// Key insight from R4 post-mortem: 8-bit level-0 bins put ~25% of a row
// into ONE LDS address (exponent clustering of N(0,1)+Gumbel data) ->
// ~2000-deep serialized LDS atomics. 12-bit bins cut the hottest bin to
// ~2-3%, and 4 group-private copies at stride 4097 (odd -> bank-shifted)
// remove cross-group bank pile-up. All scans block-parallel, 10 barriers.

#define NROW 32
#define NCOL 8192
#define KSEL 256
#define THREADS 1024
#define H0S 4097          // 4096 bins + 1 pad word (odd stride -> bank shift)

__device__ __forceinline__ unsigned float_to_key(float f) {
    unsigned u = __float_as_uint(f);
    return (u & 0x80000000u) ? ~u : (u | 0x80000000u);  // monotone
}

__global__ __launch_bounds__(THREADS) void topk_kernel(
    const float* __restrict__ logits, const float* __restrict__ noise,
    const float* __restrict__ mem, float* __restrict__ out)
{
    __shared__ unsigned hist0[4 * H0S];   // 4 wave-group-private 12-bit hists
    __shared__ __align__(16) unsigned hist1[4096];
    __shared__ unsigned hist2[256];
    __shared__ unsigned wpart[16];
    __shared__ unsigned sh_pn[2];

    const int tid  = threadIdx.x;
    const int wave = tid >> 6;
    const int lane = tid & 63;
    const int grp  = wave >> 2;           // 4 waves share one private hist
    const int base = blockIdx.x * NCOL + tid * 8;

    // ---- coalesced loads (warm in L2/L3 from harness input-restore) ----
    float4 lg0 = ((const float4*)(logits + base))[0];
    float4 lg1 = ((const float4*)(logits + base))[1];
    float4 no0 = ((const float4*)(noise  + base))[0];
    float4 no1 = ((const float4*)(noise  + base))[1];
    float4 mm0 = ((const float4*)(mem    + base))[0];
    float4 mm1 = ((const float4*)(mem    + base))[1];

    unsigned key[8];
    key[0] = float_to_key(lg0.x + no0.x + mm0.x * -1000.0f);
    key[1] = float_to_key(lg0.y + no0.y + mm0.y * -1000.0f);
    key[2] = float_to_key(lg0.z + no0.z + mm0.z * -1000.0f);
    key[3] = float_to_key(lg0.w + no0.w + mm0.w * -1000.0f);
    key[4] = float_to_key(lg1.x + no1.x + mm1.x * -1000.0f);
    key[5] = float_to_key(lg1.y + no1.y + mm1.y * -1000.0f);
    key[6] = float_to_key(lg1.z + no1.z + mm1.z * -1000.0f);
    key[7] = float_to_key(lg1.w + no1.w + mm1.w * -1000.0f);

    // ---- zero all histograms ----
#pragma unroll
    for (int i = tid; i < 4 * H0S; i += THREADS) hist0[i] = 0u;
#pragma unroll
    for (int i = tid; i < 4096; i += THREADS) hist1[i] = 0u;
    if (tid < 256) hist2[tid] = 0u;
    __syncthreads();                                     // B1

    // ---- L0: 12-bit histogram (bins = key>>20), group-private ----
    {
        unsigned* h0 = hist0 + grp * H0S;
#pragma unroll
        for (int i = 0; i < 8; ++i) atomicAdd(&h0[key[i] >> 20], 1u);
    }
    __syncthreads();                                     // B2

    unsigned need = KSEL;
    unsigned p12, p24;
    const int dbase = 4095 - 4 * tid;    // this thread's top (descending) bin

    // ---- L0 scan: thread t owns bins dbase..dbase-3 (descending) ----
    {
        unsigned c[4], tot = 0;
#pragma unroll
        for (int j = 0; j < 4; ++j) {
            const int d = dbase - j;
            c[j] = hist0[d] + hist0[H0S + d] + hist0[2 * H0S + d] + hist0[3 * H0S + d];
            tot += c[j];
        }
        unsigned s = tot;
#pragma unroll
        for (int off = 1; off < 64; off <<= 1) {
            unsigned nv = __shfl_up(s, off, 64);
            if (lane >= off) s += nv;
        }
        if (lane == 63) wpart[wave] = s;
        __syncthreads();                                 // B3
        unsigned add = 0;
        for (int w = 0; w < wave; ++w) add += wpart[w];
        unsigned cum = s + add - tot;                    // exclusive prefix
#pragma unroll
        for (int j = 0; j < 4; ++j) {
            unsigned nc = cum + c[j];
            if (nc >= need && cum < need) {
                sh_pn[0] = (unsigned)(dbase - j);
                sh_pn[1] = need - cum;
            }
            cum = nc;
        }
    }
    __syncthreads();                                     // B4
    p12 = sh_pn[0]; need = sh_pn[1];

    // ---- L1: 12-bit refine (bins = (key>>8)&4095), shared hist1 ----
#pragma unroll
    for (int i = 0; i < 8; ++i)
        if ((key[i] >> 20) == p12)
            atomicAdd(&hist1[(key[i] >> 8) & 4095u], 1u);
    __syncthreads();                                     // B5

    {
        // 16B-aligned uint4 read of 4 consecutive bins [dbase-3 .. dbase]
        uint4 v = *(const uint4*)&hist1[dbase - 3];
        unsigned c[4] = {v.w, v.z, v.y, v.x};            // descending order
        unsigned tot = c[0] + c[1] + c[2] + c[3];
        unsigned s = tot;
#pragma unroll
        for (int off = 1; off < 64; off <<= 1) {
            unsigned nv = __shfl_up(s, off, 64);
            if (lane >= off) s += nv;
        }
        if (lane == 63) wpart[wave] = s;
        __syncthreads();                                 // B6
        unsigned add = 0;
        for (int w = 0; w < wave; ++w) add += wpart[w];
        unsigned cum = s + add - tot;
#pragma unroll
        for (int j = 0; j < 4; ++j) {
            unsigned nc = cum + c[j];
            if (nc >= need && cum < need) {
                sh_pn[0] = (unsigned)(dbase - j);
                sh_pn[1] = need - cum;
            }
            cum = nc;
        }
    }
    __syncthreads();                                     // B7
    p24 = (p12 << 12) | sh_pn[0]; need = sh_pn[1];

    // ---- L2: 8-bit final (bins = key&255), shared hist2 ----
#pragma unroll
    for (int i = 0; i < 8; ++i)
        if ((key[i] >> 8) == p24)
            atomicAdd(&hist2[key[i] & 255u], 1u);
    __syncthreads();                                     // B8

    if (wave == 0) {
        const int d0 = 255 - 4 * lane;
        unsigned c0 = hist2[d0], c1 = hist2[d0 - 1],
                 c2 = hist2[d0 - 2], c3 = hist2[d0 - 3];
        unsigned tot = c0 + c1 + c2 + c3, s = tot;
#pragma unroll
        for (int off = 1; off < 64; off <<= 1) {
            unsigned nv = __shfl_up(s, off, 64);
            if (lane >= off) s += nv;
        }
        unsigned P = s - tot;
        unsigned cum0 = P + c0, cum1 = cum0 + c1, cum2 = cum1 + c2, cum3 = cum2 + c3;
        if (cum0 >= need && P < need)         { sh_pn[0] = (unsigned)d0;       sh_pn[1] = need - P;    }
        else if (cum1 >= need && cum0 < need) { sh_pn[0] = (unsigned)(d0 - 1); sh_pn[1] = need - cum0; }
        else if (cum2 >= need && cum1 < need) { sh_pn[0] = (unsigned)(d0 - 2); sh_pn[1] = need - cum1; }
        else if (cum3 >= need && cum2 < need) { sh_pn[0] = (unsigned)(d0 - 3); sh_pn[1] = need - cum2; }
    }
    __syncthreads();                                     // B9
    const unsigned T     = (p24 << 8) | sh_pn[0];        // exact K-th largest key
    const unsigned needF = sh_pn[1];                     // ties kept, lowest idx

    // ---- tie-break: exclusive count of equal keys at lower index ----
    unsigned local_eq = 0;
#pragma unroll
    for (int i = 0; i < 8; ++i) local_eq += (key[i] == T) ? 1u : 0u;
    unsigned s2 = local_eq;
#pragma unroll
    for (int off = 1; off < 64; off <<= 1) {
        unsigned nv = __shfl_up(s2, off, 64);
        if (lane >= off) s2 += nv;
    }
    if (lane == 63) wpart[wave] = s2;
    __syncthreads();                                     // B10
    unsigned rank = s2 - local_eq;
    for (int w = 0; w < wave; ++w) rank += wpart[w];

    // ---- emit: out = indicator(top-K) + sample_memory (pure stores) ----
    float o[8];
#pragma unroll
    for (int i = 0; i < 8; ++i) {
        float sel;
        if (key[i] > T)       sel = 1.0f;
        else if (key[i] == T) { sel = (rank < needF) ? 1.0f : 0.0f; ++rank; }
        else                  sel = 0.0f;
        o[i] = sel;
    }
    o[0] += mm0.x; o[1] += mm0.y; o[2] += mm0.z; o[3] += mm0.w;
    o[4] += mm1.x; o[5] += mm1.y; o[6] += mm1.z; o[7] += mm1.w;
    ((float4*)(out + base))[0] = make_float4(o[0], o[1], o[2], o[3]);
    ((float4*)(out + base))[1] = make_float4(o[4], o[5], o[6], o[7]);
}

extern "C" void kernel_launch(void* const* d_in, const int* in_sizes, int n_in,
                              void* d_out, int out_size, void* d_ws, size_t ws_size,
                              hipStream_t stream) {
    const float* logits = (const float*)d_in[0];
    const float* noise  = (const float*)d_in[1];
    const float* mem    = (const float*)d_in[2];
    float* out = (float*)d_out;

    topk_kernel<<<NROW, THREADS, 0, stream>>>(logits, noise, mem, out);
}